// Round 6
// baseline (88.911 us; speedup 1.0000x reference)
//
#include <hip/hip_runtime.h>

// entmax_bisect, alpha=1.5, rows of N=2048 fp32.
// TWO rows per wave64, solved CONCURRENTLY: every latency-critical serial
// chain (shuffle reductions, bisection recurrence, boundary sort/greedy) is
// duplicated for two independent rows and interleaved -> 2x ILP on the
// critical path. Round-5 lesson: sequential multi-row + prefetch failed
// (VGPR=60 proved the compiler sank the prefetch); concurrent-ILP needs the
// registers to be live anyway.
//
// Math (validated rounds 2-5, absmax ~1e-3 vs 2e-2 threshold):
//   v = 0.5*x - 0.5*max => max element -> exactly 0; bracket (lo,hi)=(-1,0);
//   am1=0.5 => power(d,1/am1)=d*d. All midpoints and tau lie in (-1,0], so
//   elements with v <= -1 contribute exactly 0 everywhere -> compact
//   candidates (v > -1, ~200/2048 for N(0,1)) into <=12 LDS slots per lane.
//   P1: K1=6 bisect iters on candidates (bracket 2^-6), s(lo) > 1 >= s(hi).
//   P2: aggregates (n,S1,S2) over certain support {v > hi} centered at hi;
//       boundary elements in (lo,hi] compacted (<=8).
//   P3: sort boundary desc, greedy prefix-accept (s monotone), closed-form
//       tau = hi + (S1 - sqrt(S1^2 - n(S2-1)))/n (== 50-iter bisection limit
//       to 2^-44 << fp32 rounding).
//   Fallbacks (exact): >12 candidates in any lane -> both rows run the full
//   50-iteration bisection on v[32]; >8 boundary -> remaining bisect iters
//   on the compacted set (per row).

typedef float f32x4 __attribute__((ext_vector_type(4)));

constexpr int N = 2048;
constexpr int PER_LANE = N / 64;      // 32
constexpr int WPB = 4;                // waves per 256-thread block
constexpr int CAPL = 12;              // candidate capacity per lane
constexpr int BMAX = 8;
constexpr int K1 = 6;
constexpr int TOTAL_ITER = 50;

__device__ __forceinline__ float wave_sum(float s) {
    #pragma unroll
    for (int off = 32; off >= 1; off >>= 1)
        s += __shfl_xor(s, off, 64);
    return s;
}

// Exact reference fallback: full 50-iteration bisection on the raw v[32].
__device__ __forceinline__ void full_solve_store(
        float (&v)[PER_LANE], f32x4* __restrict__ outr, int lane) {
    float lo = -1.0f, hi = 0.0f;
    for (int it = 0; it < TOTAL_ITER; ++it) {
        const float mid = 0.5f * (lo + hi);
        float s0 = 0.f, s1 = 0.f, s2 = 0.f, s3 = 0.f;
        #pragma unroll
        for (int i = 0; i < PER_LANE; i += 4) {
            float d0 = fmaxf(v[i+0] - mid, 0.f);
            float d1 = fmaxf(v[i+1] - mid, 0.f);
            float d2 = fmaxf(v[i+2] - mid, 0.f);
            float d3 = fmaxf(v[i+3] - mid, 0.f);
            s0 = fmaf(d0, d0, s0); s1 = fmaf(d1, d1, s1);
            s2 = fmaf(d2, d2, s2); s3 = fmaf(d3, d3, s3);
        }
        float s = wave_sum((s0 + s1) + (s2 + s3));
        if (s > 1.0f) lo = mid; else hi = mid;
    }
    const float tau = 0.5f * (lo + hi);
    float s0 = 0.f;
    #pragma unroll
    for (int i = 0; i < PER_LANE; ++i) {
        float d = fmaxf(v[i] - tau, 0.f);
        s0 = fmaf(d, d, s0);
    }
    const float inv = 1.0f / fmaxf(wave_sum(s0), 1e-12f);
    #pragma unroll
    for (int c = 0; c < PER_LANE / 4; ++c) {
        float d0 = fmaxf(v[4*c+0] - tau, 0.f);
        float d1 = fmaxf(v[4*c+1] - tau, 0.f);
        float d2 = fmaxf(v[4*c+2] - tau, 0.f);
        float d3 = fmaxf(v[4*c+3] - tau, 0.f);
        f32x4 t;
        t.x = (d0*d0)*inv; t.y = (d1*d1)*inv;
        t.z = (d2*d2)*inv; t.w = (d3*d3)*inv;
        outr[lane + 64 * c] = t;
    }
}

// Boundary sort + greedy + closed-form root for one row (scalar chain).
__device__ __forceinline__ float closed_form_tau(
        const float* bnd, float cth, float nA, float S1, float S2) {
    float b0 = bnd[0], b1 = bnd[1], b2 = bnd[2], b3 = bnd[3];
    float b4 = bnd[4], b5 = bnd[5], b6 = bnd[6], b7 = bnd[7];
    #define CE(a, b) { float _t = fmaxf(a, b); b = fminf(a, b); a = _t; }
    CE(b0,b1) CE(b2,b3) CE(b4,b5) CE(b6,b7)
    CE(b0,b2) CE(b1,b3) CE(b4,b6) CE(b5,b7)
    CE(b1,b2) CE(b5,b6)
    CE(b0,b4) CE(b1,b5) CE(b2,b6) CE(b3,b7)
    CE(b2,b4) CE(b3,b5)
    CE(b1,b2) CE(b3,b4) CE(b5,b6)
    #undef CE
    float nk = nA, S1k = S1, S2k = S2;
    #define STEP(bk) {                                              \
        float t_  = bk - cth;                                       \
        float sc_ = fmaf(t_, fmaf(nk, t_, -2.0f * S1k), S2k);       \
        bool  ac_ = sc_ < 1.0f;                                     \
        float ta_ = ac_ ? t_ : 0.0f;                                \
        nk  += ac_ ? 1.0f : 0.0f;                                   \
        S1k += ta_;                                                 \
        S2k  = fmaf(ta_, ta_, S2k); }
    STEP(b0) STEP(b1) STEP(b2) STEP(b3)
    STEP(b4) STEP(b5) STEP(b6) STEP(b7)
    #undef STEP
    float disc = fmaxf(fmaf(S1k, S1k, -nk * (S2k - 1.0f)), 0.0f);
    return cth + (S1k - sqrtf(disc)) / nk;
}

// Rare per-row boundary-overflow: finish remaining iterations on candidates.
__device__ __forceinline__ float bisect_tail_tau(
        float (&cd)[CAPL], float lo, float hi) {
    for (int it = 0; it < TOTAL_ITER - K1; ++it) {
        const float mid = 0.5f * (lo + hi);
        float sa = 0.f, sb = 0.f;
        #pragma unroll
        for (int k = 0; k < CAPL; k += 2) {
            float d0 = fmaxf(cd[k]   - mid, 0.f);
            float d1 = fmaxf(cd[k+1] - mid, 0.f);
            sa = fmaf(d0, d0, sa);
            sb = fmaf(d1, d1, sb);
        }
        float s = wave_sum(sa + sb);
        if (s > 1.0f) lo = mid; else hi = mid;
    }
    return 0.5f * (lo + hi);
}

__global__ __launch_bounds__(256, 4)
void entmax15_kernel(const float* __restrict__ x,
                     float* __restrict__ out, int rows) {
    __shared__ float s_cand[WPB][2][CAPL][64];   // slot-major: conflict-free
    __shared__ float s_bnd[WPB][2][BMAX];
    __shared__ int   s_cnt[WPB][2];

    const int wave = threadIdx.x >> 6;
    const int lane = threadIdx.x & 63;
    const int gw   = blockIdx.x * WPB + wave;
    const int rowA = 2 * gw;
    const int rowB = rowA + 1;
    if (rowA >= rows) return;        // rows even: rowB < rows iff rowA < rows

    const f32x4* xA = reinterpret_cast<const f32x4*>(x + (size_t)rowA * N);
    const f32x4* xB = reinterpret_cast<const f32x4*>(x + (size_t)rowB * N);
    f32x4* outA = reinterpret_cast<f32x4*>(out + (size_t)rowA * N);
    f32x4* outB = reinterpret_cast<f32x4*>(out + (size_t)rowB * N);

    // 16 loads issued back-to-back: 2x memory parallelism per wave.
    float vA[PER_LANE], vB[PER_LANE];
    #pragma unroll
    for (int c = 0; c < 8; ++c) {
        f32x4 t = xA[lane + 64 * c];
        vA[4*c+0] = t.x; vA[4*c+1] = t.y; vA[4*c+2] = t.z; vA[4*c+3] = t.w;
    }
    #pragma unroll
    for (int c = 0; c < 8; ++c) {
        f32x4 t = xB[lane + 64 * c];
        vB[4*c+0] = t.x; vB[4*c+1] = t.y; vB[4*c+2] = t.z; vB[4*c+3] = t.w;
    }

    // Interleaved row maxes.
    float mA = vA[0], mB = vB[0];
    #pragma unroll
    for (int i = 1; i < PER_LANE; ++i) {
        mA = fmaxf(mA, vA[i]);
        mB = fmaxf(mB, vB[i]);
    }
    #pragma unroll
    for (int off = 32; off >= 1; off >>= 1) {
        mA = fmaxf(mA, __shfl_xor(mA, off, 64));
        mB = fmaxf(mB, __shfl_xor(mB, off, 64));
    }

    // v = 0.5*x - 0.5*m (argmax -> exactly 0).
    const float nhA = -0.5f * mA, nhB = -0.5f * mB;
    #pragma unroll
    for (int i = 0; i < PER_LANE; ++i) {
        vA[i] = fmaf(0.5f, vA[i], nhA);
        vB[i] = fmaf(0.5f, vB[i], nhB);
    }

    // ---- Candidate compaction (both rows) ----
    #pragma unroll
    for (int k = 0; k < CAPL; ++k) {
        s_cand[wave][0][k][lane] = -1e30f;
        s_cand[wave][1][k][lane] = -1e30f;
    }
    if (lane < BMAX) { s_bnd[wave][0][lane] = -1e30f; s_bnd[wave][1][lane] = -1e30f; }
    if (lane == 0)   { s_cnt[wave][0] = 0; s_cnt[wave][1] = 0; }
    // Wave-private LDS: same-wave DS ordering suffices (no barriers needed).

    int jA = 0, jB = 0;
    #pragma unroll
    for (int i = 0; i < PER_LANE; ++i) {
        const bool cA = vA[i] > -1.0f;
        const int  sA = (jA < CAPL - 1) ? jA : (CAPL - 1);
        if (cA) s_cand[wave][0][sA][lane] = vA[i];
        jA += cA ? 1 : 0;
        const bool cB = vB[i] > -1.0f;
        const int  sB = (jB < CAPL - 1) ? jB : (CAPL - 1);
        if (cB) s_cand[wave][1][sB][lane] = vB[i];
        jB += cB ? 1 : 0;
    }

    if (__any((jA > CAPL) || (jB > CAPL))) {
        // Rare exact fallback: both rows via full reference bisection.
        full_solve_store(vA, outA, lane);
        full_solve_store(vB, outB, lane);
        return;
    }

    float cdA[CAPL], cdB[CAPL];
    #pragma unroll
    for (int k = 0; k < CAPL; ++k) {
        cdA[k] = s_cand[wave][0][k][lane];
        cdB[k] = s_cand[wave][1][k][lane];
    }

    // ---- P1: paired bisection, 2x ILP on the serial chain ----
    float loA = -1.0f, hiA = 0.0f, loB = -1.0f, hiB = 0.0f;
    #pragma unroll
    for (int it = 0; it < K1; ++it) {
        const float midA = 0.5f * (loA + hiA);
        const float midB = 0.5f * (loB + hiB);
        float a0 = 0.f, a1 = 0.f, b0 = 0.f, b1 = 0.f;
        #pragma unroll
        for (int k = 0; k < CAPL; k += 2) {
            float dA0 = fmaxf(cdA[k]   - midA, 0.f);
            float dA1 = fmaxf(cdA[k+1] - midA, 0.f);
            float dB0 = fmaxf(cdB[k]   - midB, 0.f);
            float dB1 = fmaxf(cdB[k+1] - midB, 0.f);
            a0 = fmaf(dA0, dA0, a0); a1 = fmaf(dA1, dA1, a1);
            b0 = fmaf(dB0, dB0, b0); b1 = fmaf(dB1, dB1, b1);
        }
        float sA = a0 + a1, sB = b0 + b1;
        #pragma unroll
        for (int off = 32; off >= 1; off >>= 1) {
            sA += __shfl_xor(sA, off, 64);
            sB += __shfl_xor(sB, off, 64);
        }
        loA = (sA > 1.0f) ? midA : loA;  hiA = (sA > 1.0f) ? hiA : midA;
        loB = (sB > 1.0f) ? midB : loB;  hiB = (sB > 1.0f) ? hiB : midB;
    }

    // ---- P2: paired aggregates + boundary compaction ----
    const float cthA = hiA, lofA = loA, cthB = hiB, lofB = loB;
    float nAa = 0.f, S1a = 0.f, S2a = 0.f;
    float nAb = 0.f, S1b = 0.f, S2b = 0.f;
    #pragma unroll
    for (int k = 0; k < CAPL; ++k) {
        float uA  = cdA[k] - cthA;
        float umA = fmaxf(uA, 0.f);
        nAa += (uA > 0.f) ? 1.0f : 0.0f;
        S1a += umA;
        S2a  = fmaf(umA, umA, S2a);
        if (uA <= 0.f && cdA[k] > lofA) {
            int t = atomicAdd(&s_cnt[wave][0], 1);
            if (t < BMAX) s_bnd[wave][0][t] = cdA[k];
        }
        float uB  = cdB[k] - cthB;
        float umB = fmaxf(uB, 0.f);
        nAb += (uB > 0.f) ? 1.0f : 0.0f;
        S1b += umB;
        S2b  = fmaf(umB, umB, S2b);
        if (uB <= 0.f && cdB[k] > lofB) {
            int t = atomicAdd(&s_cnt[wave][1], 1);
            if (t < BMAX) s_bnd[wave][1][t] = cdB[k];
        }
    }
    // 6-way interleaved reduction: shuffle latency shared across all six.
    #pragma unroll
    for (int off = 32; off >= 1; off >>= 1) {
        nAa += __shfl_xor(nAa, off, 64);
        S1a += __shfl_xor(S1a, off, 64);
        S2a += __shfl_xor(S2a, off, 64);
        nAb += __shfl_xor(nAb, off, 64);
        S1b += __shfl_xor(S1b, off, 64);
        S2b += __shfl_xor(S2b, off, 64);
    }

    const int cntA = s_cnt[wave][0];   // wave-uniform
    const int cntB = s_cnt[wave][1];

    float tauA = (cntA <= BMAX)
        ? closed_form_tau(s_bnd[wave][0], cthA, nAa, S1a, S2a)
        : bisect_tail_tau(cdA, loA, hiA);
    float tauB = (cntB <= BMAX)
        ? closed_form_tau(s_bnd[wave][1], cthB, nAb, S1b, S2b)
        : bisect_tail_tau(cdB, loB, hiB);

    // ---- Normalizing sums (paired) ----
    float a0 = 0.f, a1 = 0.f, b0 = 0.f, b1 = 0.f;
    #pragma unroll
    for (int k = 0; k < CAPL; k += 2) {
        float dA0 = fmaxf(cdA[k]   - tauA, 0.f);
        float dA1 = fmaxf(cdA[k+1] - tauA, 0.f);
        float dB0 = fmaxf(cdB[k]   - tauB, 0.f);
        float dB1 = fmaxf(cdB[k+1] - tauB, 0.f);
        a0 = fmaf(dA0, dA0, a0); a1 = fmaf(dA1, dA1, a1);
        b0 = fmaf(dB0, dB0, b0); b1 = fmaf(dB1, dB1, b1);
    }
    float ssA = a0 + a1, ssB = b0 + b1;
    #pragma unroll
    for (int off = 32; off >= 1; off >>= 1) {
        ssA += __shfl_xor(ssA, off, 64);
        ssB += __shfl_xor(ssB, off, 64);
    }
    const float invA = 1.0f / fmaxf(ssA, 1e-12f);
    const float invB = 1.0f / fmaxf(ssB, 1e-12f);

    // ---- Epilogue: p = max(v - tau, 0)^2 * inv ----
    #pragma unroll
    for (int c = 0; c < PER_LANE / 4; ++c) {
        float dA0 = fmaxf(vA[4*c+0] - tauA, 0.f);
        float dA1 = fmaxf(vA[4*c+1] - tauA, 0.f);
        float dA2 = fmaxf(vA[4*c+2] - tauA, 0.f);
        float dA3 = fmaxf(vA[4*c+3] - tauA, 0.f);
        f32x4 t;
        t.x = (dA0*dA0)*invA; t.y = (dA1*dA1)*invA;
        t.z = (dA2*dA2)*invA; t.w = (dA3*dA3)*invA;
        outA[lane + 64 * c] = t;
        float dB0 = fmaxf(vB[4*c+0] - tauB, 0.f);
        float dB1 = fmaxf(vB[4*c+1] - tauB, 0.f);
        float dB2 = fmaxf(vB[4*c+2] - tauB, 0.f);
        float dB3 = fmaxf(vB[4*c+3] - tauB, 0.f);
        t.x = (dB0*dB0)*invB; t.y = (dB1*dB1)*invB;
        t.z = (dB2*dB2)*invB; t.w = (dB3*dB3)*invB;
        outB[lane + 64 * c] = t;
    }
}

extern "C" void kernel_launch(void* const* d_in, const int* in_sizes, int n_in,
                              void* d_out, int out_size, void* d_ws, size_t ws_size,
                              hipStream_t stream) {
    const float* x = (const float*)d_in[0];
    float* out = (float*)d_out;
    const int rows = in_sizes[0] / N;                 // 16384
    const int pairs = rows / 2;                       // 8192 waves
    const int blocks = (pairs + WPB - 1) / WPB;       // 2048
    entmax15_kernel<<<blocks, 64 * WPB, 0, stream>>>(x, out, rows);
}

// Round 7
// 83.407 us; speedup vs baseline: 1.0660x; 1.0660x over previous
//
#include <hip/hip_runtime.h>

// entmax_bisect, alpha=1.5, rows of N=2048 fp32. One wave64 per row-slot,
// RPW=4 strided rows per wave, software-pipelined via ASYNC global->LDS
// prefetch (__builtin_amdgcn_global_load_lds): the next row streams into a
// wave-private 8KB LDS buffer while the current row's solve runs. Unlike
// rounds 5/6 (VGPR prefetch -> regalloc sank/spilled it), the async copy has
// no VGPR destination, so the compiler cannot kill the pipeline.
//
// Wait discipline: prefetch row k+1 is issued BEFORE solve k; stores of row
// k are issued after. At the top of iteration k+1 the outstanding vm ops are
// [8 loads (oldest), 8 stores]; vmcnt decrements in issue order, so
// s_waitcnt vmcnt(8) == "loads landed" without draining the stores. A
// compiler memory fence after the prefetch issue keeps that issue order.
//
// Math (validated rounds 2-6, absmax ~1e-3 vs 2e-2 threshold):
//   v = 0.5*x - 0.5*max => max element -> exactly 0; bracket (lo,hi)=(-1,0);
//   am1=0.5 => power(d,1/am1)=d*d. All midpoints and tau lie in (-1,0], so
//   elements with v <= -1 contribute exactly 0 everywhere -> compact
//   candidates (v > -1, ~140/2048 for N(0,1)) into <=12 LDS slots per lane.
//   P1: K1=6 bisect iters on candidates (bracket 2^-6), s(lo) > 1 >= s(hi).
//   P2: aggregates (n,S1,S2) over certain support {v > hi} centered at hi;
//       boundary elements in (lo,hi] compacted (<=8).
//   P3: sort boundary desc, greedy prefix-accept (s monotone), closed-form
//       tau = hi + (S1 - sqrt(S1^2 - n(S2-1)))/n (== 50-iter bisection limit
//       to 2^-44 << fp32 rounding).
//   Fallbacks (exact): >12 candidates in a lane -> full 50-iter bisection on
//   v[32]; >8 boundary -> remaining bisect iters on the compacted set.

typedef float f32x4 __attribute__((ext_vector_type(4)));

constexpr int N = 2048;
constexpr int PER_LANE = N / 64;      // 32
constexpr int WPB = 4;                // waves per 256-thread block
constexpr int RPW = 4;                // rows per wave (async pipeline)
constexpr int CAPL = 12;              // candidate capacity per lane
constexpr int BMAX = 8;
constexpr int K1 = 6;
constexpr int TOTAL_ITER = 50;

__device__ __forceinline__ float wave_sum(float s) {
    #pragma unroll
    for (int off = 32; off >= 1; off >>= 1)
        s += __shfl_xor(s, off, 64);
    return s;
}
__device__ __forceinline__ float wave_max(float m) {
    #pragma unroll
    for (int off = 32; off >= 1; off >>= 1)
        m = fmaxf(m, __shfl_xor(m, off, 64));
    return m;
}

// Issue 8 async 16B global->LDS copies for one 8KB row. LDS dest is
// wave-uniform base + lane*16 per op; global src is per-lane. No VGPR dest.
__device__ __forceinline__ void prefetch_row(const float* __restrict__ g,
                                             float* lds, int lane) {
    #pragma unroll
    for (int c = 0; c < 8; ++c) {
        __builtin_amdgcn_global_load_lds(
            (const __attribute__((address_space(1))) void*)(g + 4 * lane + 256 * c),
            (__attribute__((address_space(3))) void*)(lds + 256 * c),
            16, 0, 0);
    }
}

// Solve one row given transformed v[32]; writes p to outr.
// cand/bnd/cnt are wave-private LDS (same-wave DS ordering suffices).
__device__ __forceinline__ void solve_and_store(
        float (&v)[PER_LANE], f32x4* __restrict__ outr, int lane,
        float (&cand)[CAPL][64], float (&bnd)[BMAX], int* cntp) {

    #pragma unroll
    for (int k = 0; k < CAPL; ++k) cand[k][lane] = -1e30f;
    if (lane < BMAX) bnd[lane] = -1e30f;
    if (lane == 0)   *cntp = 0;

    int j = 0;
    #pragma unroll
    for (int i = 0; i < PER_LANE; ++i) {
        const bool c = v[i] > -1.0f;
        const int  slot = (j < CAPL - 1) ? j : (CAPL - 1);  // clamp; ovf caught
        if (c) cand[slot][lane] = v[i];
        j += c ? 1 : 0;
    }

    float tau, ssum;
    if (!__any(j > CAPL)) {
        float cd[CAPL];
        #pragma unroll
        for (int k = 0; k < CAPL; ++k) cd[k] = cand[k][lane];

        float lo = -1.0f, hi = 0.0f;
        for (int it = 0; it < K1; ++it) {
            const float mid = 0.5f * (lo + hi);
            float sa = 0.f, sb = 0.f;
            #pragma unroll
            for (int k = 0; k < CAPL; k += 2) {
                float d0 = fmaxf(cd[k]   - mid, 0.f);
                float d1 = fmaxf(cd[k+1] - mid, 0.f);
                sa = fmaf(d0, d0, sa);
                sb = fmaf(d1, d1, sb);
            }
            float s = wave_sum(sa + sb);
            if (s > 1.0f) lo = mid; else hi = mid;
        }

        const float cth = hi, lof = lo;
        float nA = 0.f, S1 = 0.f, S2 = 0.f;
        #pragma unroll
        for (int k = 0; k < CAPL; ++k) {
            float u  = cd[k] - cth;
            float um = fmaxf(u, 0.f);
            nA += (u > 0.f) ? 1.0f : 0.0f;
            S1 += um;
            S2  = fmaf(um, um, S2);
            if (u <= 0.f && cd[k] > lof) {          // boundary: rare
                int t = atomicAdd(cntp, 1);
                if (t < BMAX) bnd[t] = cd[k];
            }
        }
        nA = wave_sum(nA); S1 = wave_sum(S1); S2 = wave_sum(S2);

        const int cnt = *cntp;                      // wave-uniform
        if (cnt <= BMAX) {
            float b0 = bnd[0], b1 = bnd[1], b2 = bnd[2], b3 = bnd[3];
            float b4 = bnd[4], b5 = bnd[5], b6 = bnd[6], b7 = bnd[7];
            #define CE(a, b) { float _t = fmaxf(a, b); b = fminf(a, b); a = _t; }
            CE(b0,b1) CE(b2,b3) CE(b4,b5) CE(b6,b7)
            CE(b0,b2) CE(b1,b3) CE(b4,b6) CE(b5,b7)
            CE(b1,b2) CE(b5,b6)
            CE(b0,b4) CE(b1,b5) CE(b2,b6) CE(b3,b7)
            CE(b2,b4) CE(b3,b5)
            CE(b1,b2) CE(b3,b4) CE(b5,b6)
            #undef CE
            float nk = nA, S1k = S1, S2k = S2;
            #define STEP(bk) {                                              \
                float t_  = bk - cth;                                       \
                float sc_ = fmaf(t_, fmaf(nk, t_, -2.0f * S1k), S2k);       \
                bool  ac_ = sc_ < 1.0f;                                     \
                float ta_ = ac_ ? t_ : 0.0f;                                \
                nk  += ac_ ? 1.0f : 0.0f;                                   \
                S1k += ta_;                                                 \
                S2k  = fmaf(ta_, ta_, S2k); }
            STEP(b0) STEP(b1) STEP(b2) STEP(b3)
            STEP(b4) STEP(b5) STEP(b6) STEP(b7)
            #undef STEP
            float disc = fmaxf(fmaf(S1k, S1k, -nk * (S2k - 1.0f)), 0.0f);
            tau = cth + (S1k - sqrtf(disc)) / nk;
        } else {
            for (int it = 0; it < TOTAL_ITER - K1; ++it) {
                const float mid = 0.5f * (lo + hi);
                float sa = 0.f, sb = 0.f;
                #pragma unroll
                for (int k = 0; k < CAPL; k += 2) {
                    float d0 = fmaxf(cd[k]   - mid, 0.f);
                    float d1 = fmaxf(cd[k+1] - mid, 0.f);
                    sa = fmaf(d0, d0, sa);
                    sb = fmaf(d1, d1, sb);
                }
                float s = wave_sum(sa + sb);
                if (s > 1.0f) lo = mid; else hi = mid;
            }
            tau = 0.5f * (lo + hi);
        }

        float sa = 0.f, sb = 0.f;
        #pragma unroll
        for (int k = 0; k < CAPL; k += 2) {
            float d0 = fmaxf(cd[k]   - tau, 0.f);
            float d1 = fmaxf(cd[k+1] - tau, 0.f);
            sa = fmaf(d0, d0, sa);
            sb = fmaf(d1, d1, sb);
        }
        ssum = wave_sum(sa + sb);
    } else {
        // Lane-overflow fallback: full 50-iteration bisection on v.
        float lo = -1.0f, hi = 0.0f;
        for (int it = 0; it < TOTAL_ITER; ++it) {
            const float mid = 0.5f * (lo + hi);
            float s0 = 0.f, s1_ = 0.f, s2_ = 0.f, s3_ = 0.f;
            #pragma unroll
            for (int i = 0; i < PER_LANE; i += 4) {
                float d0 = fmaxf(v[i+0] - mid, 0.f);
                float d1 = fmaxf(v[i+1] - mid, 0.f);
                float d2 = fmaxf(v[i+2] - mid, 0.f);
                float d3 = fmaxf(v[i+3] - mid, 0.f);
                s0 = fmaf(d0, d0, s0); s1_ = fmaf(d1, d1, s1_);
                s2_ = fmaf(d2, d2, s2_); s3_ = fmaf(d3, d3, s3_);
            }
            float s = wave_sum((s0 + s1_) + (s2_ + s3_));
            if (s > 1.0f) lo = mid; else hi = mid;
        }
        tau = 0.5f * (lo + hi);
        float s0 = 0.f;
        #pragma unroll
        for (int i = 0; i < PER_LANE; ++i) {
            float d = fmaxf(v[i] - tau, 0.f);
            s0 = fmaf(d, d, s0);
        }
        ssum = wave_sum(s0);
    }

    const float inv = 1.0f / fmaxf(ssum, 1e-12f);
    #pragma unroll
    for (int c = 0; c < PER_LANE / 4; ++c) {
        float d0 = fmaxf(v[4*c+0] - tau, 0.f);
        float d1 = fmaxf(v[4*c+1] - tau, 0.f);
        float d2 = fmaxf(v[4*c+2] - tau, 0.f);
        float d3 = fmaxf(v[4*c+3] - tau, 0.f);
        f32x4 t;
        t.x = (d0 * d0) * inv;
        t.y = (d1 * d1) * inv;
        t.z = (d2 * d2) * inv;
        t.w = (d3 * d3) * inv;
        outr[lane + 64 * c] = t;
    }
}

__global__ __launch_bounds__(256, 3)
void entmax15_kernel(const float* __restrict__ x,
                     float* __restrict__ out, int rows) {
    __shared__ float s_stage[WPB][N];            // 8KB per wave
    __shared__ float s_cand[WPB][CAPL][64];      // slot-major: conflict-free
    __shared__ float s_bnd[WPB][BMAX];
    __shared__ int   s_cnt[WPB];

    const int wave = threadIdx.x >> 6;
    const int lane = threadIdx.x & 63;
    const int gw   = blockIdx.x * WPB + wave;    // global wave id
    const int nw   = gridDim.x * WPB;            // rows / RPW (strided rows)

    float* stage = s_stage[wave];

    if (gw < rows) prefetch_row(x + (size_t)gw * N, stage, lane);

    #pragma unroll
    for (int k = 0; k < RPW; ++k) {
        const int row = gw + k * nw;
        if (row >= rows) return;

        // Wait for row k's async loads. k>0: [8 loads (oldest), 8 stores of
        // row k-1] are outstanding; vmcnt(8) = oldest 8 retired = loads done.
        if (k == 0) asm volatile("s_waitcnt vmcnt(0)" ::: "memory");
        else        asm volatile("s_waitcnt vmcnt(8)" ::: "memory");

        // LDS -> registers (same layout the prefetch wrote).
        float v[PER_LANE];
        {
            const f32x4* sp = reinterpret_cast<const f32x4*>(stage);
            #pragma unroll
            for (int c = 0; c < 8; ++c) {
                f32x4 t = sp[lane + 64 * c];
                v[4*c+0] = t.x; v[4*c+1] = t.y;
                v[4*c+2] = t.z; v[4*c+3] = t.w;
            }
        }
        // All ds_reads retired before the stage buffer is rewritten.
        asm volatile("s_waitcnt lgkmcnt(0)" ::: "memory");
        __builtin_amdgcn_sched_barrier(0);

        // Issue next row's async loads NOW; solve below hides their latency.
        if (k + 1 < RPW) {
            const int nrow = gw + (k + 1) * nw;
            if (nrow < rows) prefetch_row(x + (size_t)nrow * N, stage, lane);
        }
        // Keep all later memory ops (stores) AFTER the prefetch issue:
        // the vmcnt(8) accounting above depends on this issue order.
        __builtin_amdgcn_sched_barrier(0);
        asm volatile("" ::: "memory");

        // Row max, then v = 0.5*x - 0.5*m (argmax -> exactly 0).
        float m = v[0];
        #pragma unroll
        for (int i = 1; i < PER_LANE; ++i) m = fmaxf(m, v[i]);
        m = wave_max(m);
        const float nhm = -0.5f * m;
        #pragma unroll
        for (int i = 0; i < PER_LANE; ++i) v[i] = fmaf(0.5f, v[i], nhm);

        f32x4* outr = reinterpret_cast<f32x4*>(out + (size_t)row * N);
        solve_and_store(v, outr, lane, s_cand[wave], s_bnd[wave], &s_cnt[wave]);
    }
}

extern "C" void kernel_launch(void* const* d_in, const int* in_sizes, int n_in,
                              void* d_out, int out_size, void* d_ws, size_t ws_size,
                              hipStream_t stream) {
    const float* x = (const float*)d_in[0];
    float* out = (float*)d_out;
    const int rows = in_sizes[0] / N;                 // 16384
    const int nwaves = (rows + RPW - 1) / RPW;        // 4096 (rows % RPW == 0)
    const int blocks = (nwaves + WPB - 1) / WPB;      // 1024
    entmax15_kernel<<<blocks, 64 * WPB, 0, stream>>>(x, out, rows);
}

// Round 8
// 75.116 us; speedup vs baseline: 1.1837x; 1.1104x over previous
//
#include <hip/hip_runtime.h>

// entmax_bisect, alpha=1.5, rows of N=2048 fp32. One wave64 per row (16384
// waves: TLP is what hides latency here — rounds 5/6/7 all proved that
// trading wave-count for per-wave pipelining loses).
//
// Round-8 change vs round-4 (57.8us): all cross-lane reductions use DPP
// (VALU pipe, ~4-8 cyc/step) instead of __shfl_xor (ds_* ops, ~35 cyc/step),
// and the reduced value is moved to an SGPR via readlane(63) so the entire
// bisection recurrence (lo/hi/mid, s>1) is wave-uniform scalar. This cuts
// ~1900 cyc of serial DS latency off the ~3800-cyc per-row critical path.
//
// Math (validated rounds 2-7, absmax ~1e-3 vs 2e-2 threshold):
//   v = 0.5*x - 0.5*max => max element -> exactly 0; bracket (lo,hi)=(-1,0);
//   am1=0.5 => power(d,1/am1)=d*d. All midpoints and tau lie in (-1,0], so
//   elements with v <= -1 contribute exactly 0 everywhere -> compact
//   candidates (v > -1, ~140/2048 for N(0,1)) into <=12 LDS slots per lane.
//   P1: K1=6 bisect iters on candidates (bracket 2^-6), s(lo) > 1 >= s(hi).
//   P2: aggregates (n,S1,S2) over certain support {v > hi} centered at hi;
//       boundary elements in (lo,hi] compacted (<=8).
//   P3: sort boundary desc, greedy prefix-accept (s monotone), closed-form
//       tau = hi + (S1 - sqrt(S1^2 - n(S2-1)))/n (== 50-iter bisection limit
//       to 2^-44 << fp32 rounding).
//   Fallbacks (exact): >12 candidates in a lane -> full 50-iter bisection on
//   v[32]; >8 boundary -> remaining bisect iters on the compacted set.

typedef float f32x4 __attribute__((ext_vector_type(4)));

constexpr int N = 2048;
constexpr int PER_LANE = N / 64;      // 32
constexpr int WPB = 4;                // waves per 256-thread block
constexpr int CAPL = 12;              // candidate capacity per lane
constexpr int BMAX = 8;
constexpr int K1 = 6;
constexpr int TOTAL_ITER = 50;

// ---- DPP wave64 reductions (VALU pipe; no ds_* latency) ----
// update_dpp: lanes not selected by row_mask receive `old`.
template <int CTRL, int RMASK>
__device__ __forceinline__ float fdpp(float old, float s) {
    return __int_as_float(__builtin_amdgcn_update_dpp(
        __float_as_int(old), __float_as_int(s), CTRL, RMASK, 0xF, false));
}

// Full-wave sum; returns the total as a wave-uniform (SGPR) value.
__device__ __forceinline__ float wave_sum_u(float s) {
    s += fdpp<0xB1, 0xF>(s, s);    // quad_perm [1,0,3,2]  (xor 1)
    s += fdpp<0x4E, 0xF>(s, s);    // quad_perm [2,3,0,1]  (xor 2)
    s += fdpp<0x141, 0xF>(s, s);   // row_half_mirror      (8-group)
    s += fdpp<0x140, 0xF>(s, s);   // row_mirror           (16-group)
    s += fdpp<0x142, 0xA>(0.0f, s);// row_bcast:15 -> rows 1,3
    s += fdpp<0x143, 0xC>(0.0f, s);// row_bcast:31 -> rows 2,3
    return __int_as_float(__builtin_amdgcn_readlane(__float_as_int(s), 63));
}

// Full-wave max; returns wave-uniform max.
__device__ __forceinline__ float wave_max_u(float m) {
    m = fmaxf(m, fdpp<0xB1, 0xF>(m, m));
    m = fmaxf(m, fdpp<0x4E, 0xF>(m, m));
    m = fmaxf(m, fdpp<0x141, 0xF>(m, m));
    m = fmaxf(m, fdpp<0x140, 0xF>(m, m));
    m = fmaxf(m, fdpp<0x142, 0xA>(m, m));  // masked lanes: fmax(m,m)=m
    m = fmaxf(m, fdpp<0x143, 0xC>(m, m));
    return __int_as_float(__builtin_amdgcn_readlane(__float_as_int(m), 63));
}

__global__ __launch_bounds__(256, 8)
void entmax15_kernel(const float* __restrict__ x,
                     float* __restrict__ out, int rows) {
    __shared__ float s_cand[WPB][CAPL][64];   // slot-major: conflict-free
    __shared__ float s_bnd[WPB][BMAX];
    __shared__ int   s_cnt[WPB];

    const int wave = threadIdx.x >> 6;
    const int lane = threadIdx.x & 63;
    const int row  = blockIdx.x * WPB + wave;
    if (row >= rows) return;          // rows % WPB == 0: never divergent

    const f32x4* xr   = reinterpret_cast<const f32x4*>(x + (size_t)row * N);
    f32x4*       outr = reinterpret_cast<f32x4*>(out + (size_t)row * N);

    float v[PER_LANE];
    #pragma unroll
    for (int c = 0; c < PER_LANE / 4; ++c) {
        f32x4 t = xr[lane + 64 * c];
        v[4*c+0] = t.x; v[4*c+1] = t.y; v[4*c+2] = t.z; v[4*c+3] = t.w;
    }

    // Row max (wave-uniform scalar result).
    float ml = v[0];
    #pragma unroll
    for (int i = 1; i < PER_LANE; ++i) ml = fmaxf(ml, v[i]);
    const float m = wave_max_u(ml);

    // v = 0.5*x - 0.5*m (argmax -> exactly 0).
    const float nhm = -0.5f * m;
    #pragma unroll
    for (int i = 0; i < PER_LANE; ++i) v[i] = fmaf(0.5f, v[i], nhm);

    // ---- Candidate compaction: v > -1 into per-lane LDS slots ----
    #pragma unroll
    for (int k = 0; k < CAPL; ++k) s_cand[wave][k][lane] = -1e30f;
    if (lane < BMAX) s_bnd[wave][lane] = -1e30f;
    if (lane == 0)   s_cnt[wave] = 0;
    // Wave-private LDS: same-wave DS ordering suffices (no barriers).

    int j = 0;
    #pragma unroll
    for (int i = 0; i < PER_LANE; ++i) {
        const bool c = v[i] > -1.0f;
        const int  slot = (j < CAPL - 1) ? j : (CAPL - 1);  // clamp; ovf caught
        if (c) s_cand[wave][slot][lane] = v[i];
        j += c ? 1 : 0;
    }

    float tau, ssum;
    if (!__any(j > CAPL)) {
        float cd[CAPL];
        #pragma unroll
        for (int k = 0; k < CAPL; ++k) cd[k] = s_cand[wave][k][lane];

        // ---- P1: 6 bisect iters; lo/hi/mid wave-uniform (scalar) ----
        float lo = -1.0f, hi = 0.0f;
        #pragma unroll
        for (int it = 0; it < K1; ++it) {
            const float mid = 0.5f * (lo + hi);
            float sa = 0.f, sb = 0.f;
            #pragma unroll
            for (int k = 0; k < CAPL; k += 2) {
                float d0 = fmaxf(cd[k]   - mid, 0.f);
                float d1 = fmaxf(cd[k+1] - mid, 0.f);
                sa = fmaf(d0, d0, sa);
                sb = fmaf(d1, d1, sb);
            }
            const float s = wave_sum_u(sa + sb);     // uniform
            const bool gt = s > 1.0f;                // scalar compare
            lo = gt ? mid : lo;
            hi = gt ? hi : mid;
        }

        // ---- P2: aggregates over certain support + boundary compaction ----
        const float cth = hi, lof = lo;
        float nA = 0.f, S1 = 0.f, S2 = 0.f;
        #pragma unroll
        for (int k = 0; k < CAPL; ++k) {
            float u  = cd[k] - cth;
            float um = fmaxf(u, 0.f);
            nA += (u > 0.f) ? 1.0f : 0.0f;
            S1 += um;
            S2  = fmaf(um, um, S2);
            if (u <= 0.f && cd[k] > lof) {          // boundary: rare
                int t = atomicAdd(&s_cnt[wave], 1);
                if (t < BMAX) s_bnd[wave][t] = cd[k];
            }
        }
        nA = wave_sum_u(nA);
        S1 = wave_sum_u(S1);
        S2 = wave_sum_u(S2);

        const int cnt = s_cnt[wave];                // wave-uniform
        if (cnt <= BMAX) {
            float b0 = s_bnd[wave][0], b1 = s_bnd[wave][1];
            float b2 = s_bnd[wave][2], b3 = s_bnd[wave][3];
            float b4 = s_bnd[wave][4], b5 = s_bnd[wave][5];
            float b6 = s_bnd[wave][6], b7 = s_bnd[wave][7];
            // Sort descending (Batcher, 19 CEs); sentinels sink.
            #define CE(a, b) { float _t = fmaxf(a, b); b = fminf(a, b); a = _t; }
            CE(b0,b1) CE(b2,b3) CE(b4,b5) CE(b6,b7)
            CE(b0,b2) CE(b1,b3) CE(b4,b6) CE(b5,b7)
            CE(b1,b2) CE(b5,b6)
            CE(b0,b4) CE(b1,b5) CE(b2,b6) CE(b3,b7)
            CE(b2,b4) CE(b3,b5)
            CE(b1,b2) CE(b3,b4) CE(b5,b6)
            #undef CE
            // Greedy prefix-accept (sentinels: s=+inf => reject).
            float nk = nA, S1k = S1, S2k = S2;
            #define STEP(bk) {                                              \
                float t_  = bk - cth;                                       \
                float sc_ = fmaf(t_, fmaf(nk, t_, -2.0f * S1k), S2k);       \
                bool  ac_ = sc_ < 1.0f;                                     \
                float ta_ = ac_ ? t_ : 0.0f;                                \
                nk  += ac_ ? 1.0f : 0.0f;                                   \
                S1k += ta_;                                                 \
                S2k  = fmaf(ta_, ta_, S2k); }
            STEP(b0) STEP(b1) STEP(b2) STEP(b3)
            STEP(b4) STEP(b5) STEP(b6) STEP(b7)
            #undef STEP
            float disc = fmaxf(fmaf(S1k, S1k, -nk * (S2k - 1.0f)), 0.0f);
            tau = cth + (S1k - sqrtf(disc)) / nk;
        } else {
            // Boundary overflow: finish all remaining reference iterations
            // on the compacted set (non-candidates contribute exactly 0).
            for (int it = 0; it < TOTAL_ITER - K1; ++it) {
                const float mid = 0.5f * (lo + hi);
                float sa = 0.f, sb = 0.f;
                #pragma unroll
                for (int k = 0; k < CAPL; k += 2) {
                    float d0 = fmaxf(cd[k]   - mid, 0.f);
                    float d1 = fmaxf(cd[k+1] - mid, 0.f);
                    sa = fmaf(d0, d0, sa);
                    sb = fmaf(d1, d1, sb);
                }
                const float s = wave_sum_u(sa + sb);
                const bool gt = s > 1.0f;
                lo = gt ? mid : lo;
                hi = gt ? hi : mid;
            }
            tau = 0.5f * (lo + hi);
        }

        // Normalizing sum from candidates (non-candidates are exactly 0).
        float sa = 0.f, sb = 0.f;
        #pragma unroll
        for (int k = 0; k < CAPL; k += 2) {
            float d0 = fmaxf(cd[k]   - tau, 0.f);
            float d1 = fmaxf(cd[k+1] - tau, 0.f);
            sa = fmaf(d0, d0, sa);
            sb = fmaf(d1, d1, sb);
        }
        ssum = wave_sum_u(sa + sb);
    } else {
        // ---- Lane-overflow fallback: full 50-iteration bisection on v ----
        float lo = -1.0f, hi = 0.0f;
        for (int it = 0; it < TOTAL_ITER; ++it) {
            const float mid = 0.5f * (lo + hi);
            float s0 = 0.f, s1_ = 0.f, s2_ = 0.f, s3_ = 0.f;
            #pragma unroll
            for (int i = 0; i < PER_LANE; i += 4) {
                float d0 = fmaxf(v[i+0] - mid, 0.f);
                float d1 = fmaxf(v[i+1] - mid, 0.f);
                float d2 = fmaxf(v[i+2] - mid, 0.f);
                float d3 = fmaxf(v[i+3] - mid, 0.f);
                s0 = fmaf(d0, d0, s0); s1_ = fmaf(d1, d1, s1_);
                s2_ = fmaf(d2, d2, s2_); s3_ = fmaf(d3, d3, s3_);
            }
            const float s = wave_sum_u((s0 + s1_) + (s2_ + s3_));
            const bool gt = s > 1.0f;
            lo = gt ? mid : lo;
            hi = gt ? hi : mid;
        }
        tau = 0.5f * (lo + hi);
        float s0 = 0.f;
        #pragma unroll
        for (int i = 0; i < PER_LANE; ++i) {
            float d = fmaxf(v[i] - tau, 0.f);
            s0 = fmaf(d, d, s0);
        }
        ssum = wave_sum_u(s0);
    }

    // ---- Epilogue: p = max(v - tau, 0)^2 * inv ----
    const float inv = 1.0f / fmaxf(ssum, 1e-12f);
    #pragma unroll
    for (int c = 0; c < PER_LANE / 4; ++c) {
        float d0 = fmaxf(v[4*c+0] - tau, 0.f);
        float d1 = fmaxf(v[4*c+1] - tau, 0.f);
        float d2 = fmaxf(v[4*c+2] - tau, 0.f);
        float d3 = fmaxf(v[4*c+3] - tau, 0.f);
        f32x4 t;
        t.x = (d0 * d0) * inv;
        t.y = (d1 * d1) * inv;
        t.z = (d2 * d2) * inv;
        t.w = (d3 * d3) * inv;
        outr[lane + 64 * c] = t;
    }
}

extern "C" void kernel_launch(void* const* d_in, const int* in_sizes, int n_in,
                              void* d_out, int out_size, void* d_ws, size_t ws_size,
                              hipStream_t stream) {
    const float* x = (const float*)d_in[0];
    float* out = (float*)d_out;
    const int rows = in_sizes[0] / N;                 // 16384
    const int blocks = (rows + WPB - 1) / WPB;        // 4096
    entmax15_kernel<<<blocks, 64 * WPB, 0, stream>>>(x, out, rows);
}

// Round 9
// 52.788 us; speedup vs baseline: 1.6843x; 1.4230x over previous
//
#include <hip/hip_runtime.h>

// entmax_bisect, alpha=1.5, rows of N=2048 fp32. One wave64 per row (16384
// waves: TLP hides latency — rounds 5/6/7 proved trading wave-count for
// per-wave pipelining loses).
//
// Round-9 = round-8's DPP reductions with the register cap FIXED:
// __launch_bounds__(256,4) (128 VGPR). Round-8's (256,8) forced a 64-VGPR
// cap -> v[32]+cd[12] spilled to scratch (VGPR=32, FETCH +33MB, WRITE +65MB,
// 75us). Round-6 and round-8 are the same failure family: the live-register
// budget must match the algorithm's working set.
//
// DPP: cross-lane reductions run on the VALU pipe (~4-8 cyc/step) instead of
// ds_swizzle (~35 cyc/step); reduced value lands in an SGPR via readlane(63)
// so the bisection recurrence (lo/hi/mid, s>1) is wave-uniform scalar.
//
// Math (validated rounds 2-8, absmax ~1e-3 vs 2e-2 threshold):
//   v = 0.5*x - 0.5*max => max element -> exactly 0; bracket (lo,hi)=(-1,0);
//   am1=0.5 => power(d,1/am1)=d*d. All midpoints and tau lie in (-1,0], so
//   elements with v <= -1 contribute exactly 0 everywhere -> compact
//   candidates (v > -1, ~140/2048 for N(0,1)) into <=12 LDS slots per lane.
//   P1: K1=6 bisect iters on candidates (bracket 2^-6), s(lo) > 1 >= s(hi).
//   P2: aggregates (n,S1,S2) over certain support {v > hi} centered at hi;
//       boundary elements in (lo,hi] compacted (<=8).
//   P3: sort boundary desc, greedy prefix-accept (s monotone), closed-form
//       tau = hi + (S1 - sqrt(S1^2 - n(S2-1)))/n (== 50-iter bisection limit
//       to 2^-44 << fp32 rounding).
//   Fallbacks (exact): >12 candidates in a lane -> full 50-iter bisection on
//   v[32]; >8 boundary -> remaining bisect iters on the compacted set.

typedef float f32x4 __attribute__((ext_vector_type(4)));

constexpr int N = 2048;
constexpr int PER_LANE = N / 64;      // 32
constexpr int WPB = 4;                // waves per 256-thread block
constexpr int CAPL = 12;              // candidate capacity per lane
constexpr int BMAX = 8;
constexpr int K1 = 6;
constexpr int TOTAL_ITER = 50;

// ---- DPP wave64 reductions (VALU pipe; no ds_* latency) ----
// update_dpp: lanes not selected by row_mask receive `old`.
template <int CTRL, int RMASK>
__device__ __forceinline__ float fdpp(float old, float s) {
    return __int_as_float(__builtin_amdgcn_update_dpp(
        __float_as_int(old), __float_as_int(s), CTRL, RMASK, 0xF, false));
}

// Full-wave sum; returns the total as a wave-uniform (SGPR) value.
__device__ __forceinline__ float wave_sum_u(float s) {
    s += fdpp<0xB1, 0xF>(s, s);    // quad_perm [1,0,3,2]  (xor 1)
    s += fdpp<0x4E, 0xF>(s, s);    // quad_perm [2,3,0,1]  (xor 2)
    s += fdpp<0x141, 0xF>(s, s);   // row_half_mirror      (8-group)
    s += fdpp<0x140, 0xF>(s, s);   // row_mirror           (16-group)
    s += fdpp<0x142, 0xA>(0.0f, s);// row_bcast:15 -> rows 1,3
    s += fdpp<0x143, 0xC>(0.0f, s);// row_bcast:31 -> rows 2,3
    return __int_as_float(__builtin_amdgcn_readlane(__float_as_int(s), 63));
}

// Full-wave max; returns wave-uniform max.
__device__ __forceinline__ float wave_max_u(float m) {
    m = fmaxf(m, fdpp<0xB1, 0xF>(m, m));
    m = fmaxf(m, fdpp<0x4E, 0xF>(m, m));
    m = fmaxf(m, fdpp<0x141, 0xF>(m, m));
    m = fmaxf(m, fdpp<0x140, 0xF>(m, m));
    m = fmaxf(m, fdpp<0x142, 0xA>(m, m));  // masked lanes: fmax(m,m)=m
    m = fmaxf(m, fdpp<0x143, 0xC>(m, m));
    return __int_as_float(__builtin_amdgcn_readlane(__float_as_int(m), 63));
}

__global__ __launch_bounds__(256, 4)
void entmax15_kernel(const float* __restrict__ x,
                     float* __restrict__ out, int rows) {
    __shared__ float s_cand[WPB][CAPL][64];   // slot-major: conflict-free
    __shared__ float s_bnd[WPB][BMAX];
    __shared__ int   s_cnt[WPB];

    const int wave = threadIdx.x >> 6;
    const int lane = threadIdx.x & 63;
    const int row  = blockIdx.x * WPB + wave;
    if (row >= rows) return;          // rows % WPB == 0: never divergent

    const f32x4* xr   = reinterpret_cast<const f32x4*>(x + (size_t)row * N);
    f32x4*       outr = reinterpret_cast<f32x4*>(out + (size_t)row * N);

    float v[PER_LANE];
    #pragma unroll
    for (int c = 0; c < PER_LANE / 4; ++c) {
        f32x4 t = xr[lane + 64 * c];
        v[4*c+0] = t.x; v[4*c+1] = t.y; v[4*c+2] = t.z; v[4*c+3] = t.w;
    }

    // Row max (wave-uniform scalar result).
    float ml = v[0];
    #pragma unroll
    for (int i = 1; i < PER_LANE; ++i) ml = fmaxf(ml, v[i]);
    const float m = wave_max_u(ml);

    // v = 0.5*x - 0.5*m (argmax -> exactly 0).
    const float nhm = -0.5f * m;
    #pragma unroll
    for (int i = 0; i < PER_LANE; ++i) v[i] = fmaf(0.5f, v[i], nhm);

    // ---- Candidate compaction: v > -1 into per-lane LDS slots ----
    #pragma unroll
    for (int k = 0; k < CAPL; ++k) s_cand[wave][k][lane] = -1e30f;
    if (lane < BMAX) s_bnd[wave][lane] = -1e30f;
    if (lane == 0)   s_cnt[wave] = 0;
    // Wave-private LDS: same-wave DS ordering suffices (no barriers).

    int j = 0;
    #pragma unroll
    for (int i = 0; i < PER_LANE; ++i) {
        const bool c = v[i] > -1.0f;
        const int  slot = (j < CAPL - 1) ? j : (CAPL - 1);  // clamp; ovf caught
        if (c) s_cand[wave][slot][lane] = v[i];
        j += c ? 1 : 0;
    }

    float tau, ssum;
    if (!__any(j > CAPL)) {
        float cd[CAPL];
        #pragma unroll
        for (int k = 0; k < CAPL; ++k) cd[k] = s_cand[wave][k][lane];

        // ---- P1: 6 bisect iters; lo/hi/mid wave-uniform (scalar) ----
        float lo = -1.0f, hi = 0.0f;
        #pragma unroll
        for (int it = 0; it < K1; ++it) {
            const float mid = 0.5f * (lo + hi);
            float sa = 0.f, sb = 0.f;
            #pragma unroll
            for (int k = 0; k < CAPL; k += 2) {
                float d0 = fmaxf(cd[k]   - mid, 0.f);
                float d1 = fmaxf(cd[k+1] - mid, 0.f);
                sa = fmaf(d0, d0, sa);
                sb = fmaf(d1, d1, sb);
            }
            const float s = wave_sum_u(sa + sb);     // uniform
            const bool gt = s > 1.0f;                // scalar compare
            lo = gt ? mid : lo;
            hi = gt ? hi : mid;
        }

        // ---- P2: aggregates over certain support + boundary compaction ----
        const float cth = hi, lof = lo;
        float nA = 0.f, S1 = 0.f, S2 = 0.f;
        #pragma unroll
        for (int k = 0; k < CAPL; ++k) {
            float u  = cd[k] - cth;
            float um = fmaxf(u, 0.f);
            nA += (u > 0.f) ? 1.0f : 0.0f;
            S1 += um;
            S2  = fmaf(um, um, S2);
            if (u <= 0.f && cd[k] > lof) {          // boundary: rare
                int t = atomicAdd(&s_cnt[wave], 1);
                if (t < BMAX) s_bnd[wave][t] = cd[k];
            }
        }
        nA = wave_sum_u(nA);
        S1 = wave_sum_u(S1);
        S2 = wave_sum_u(S2);

        const int cnt = s_cnt[wave];                // wave-uniform
        if (cnt <= BMAX) {
            float b0 = s_bnd[wave][0], b1 = s_bnd[wave][1];
            float b2 = s_bnd[wave][2], b3 = s_bnd[wave][3];
            float b4 = s_bnd[wave][4], b5 = s_bnd[wave][5];
            float b6 = s_bnd[wave][6], b7 = s_bnd[wave][7];
            // Sort descending (Batcher, 19 CEs); sentinels sink.
            #define CE(a, b) { float _t = fmaxf(a, b); b = fminf(a, b); a = _t; }
            CE(b0,b1) CE(b2,b3) CE(b4,b5) CE(b6,b7)
            CE(b0,b2) CE(b1,b3) CE(b4,b6) CE(b5,b7)
            CE(b1,b2) CE(b5,b6)
            CE(b0,b4) CE(b1,b5) CE(b2,b6) CE(b3,b7)
            CE(b2,b4) CE(b3,b5)
            CE(b1,b2) CE(b3,b4) CE(b5,b6)
            #undef CE
            // Greedy prefix-accept (sentinels: s=+inf => reject).
            float nk = nA, S1k = S1, S2k = S2;
            #define STEP(bk) {                                              \
                float t_  = bk - cth;                                       \
                float sc_ = fmaf(t_, fmaf(nk, t_, -2.0f * S1k), S2k);       \
                bool  ac_ = sc_ < 1.0f;                                     \
                float ta_ = ac_ ? t_ : 0.0f;                                \
                nk  += ac_ ? 1.0f : 0.0f;                                   \
                S1k += ta_;                                                 \
                S2k  = fmaf(ta_, ta_, S2k); }
            STEP(b0) STEP(b1) STEP(b2) STEP(b3)
            STEP(b4) STEP(b5) STEP(b6) STEP(b7)
            #undef STEP
            float disc = fmaxf(fmaf(S1k, S1k, -nk * (S2k - 1.0f)), 0.0f);
            tau = cth + (S1k - sqrtf(disc)) / nk;
        } else {
            // Boundary overflow: finish all remaining reference iterations
            // on the compacted set (non-candidates contribute exactly 0).
            for (int it = 0; it < TOTAL_ITER - K1; ++it) {
                const float mid = 0.5f * (lo + hi);
                float sa = 0.f, sb = 0.f;
                #pragma unroll
                for (int k = 0; k < CAPL; k += 2) {
                    float d0 = fmaxf(cd[k]   - mid, 0.f);
                    float d1 = fmaxf(cd[k+1] - mid, 0.f);
                    sa = fmaf(d0, d0, sa);
                    sb = fmaf(d1, d1, sb);
                }
                const float s = wave_sum_u(sa + sb);
                const bool gt = s > 1.0f;
                lo = gt ? mid : lo;
                hi = gt ? hi : mid;
            }
            tau = 0.5f * (lo + hi);
        }

        // Normalizing sum from candidates (non-candidates are exactly 0).
        float sa = 0.f, sb = 0.f;
        #pragma unroll
        for (int k = 0; k < CAPL; k += 2) {
            float d0 = fmaxf(cd[k]   - tau, 0.f);
            float d1 = fmaxf(cd[k+1] - tau, 0.f);
            sa = fmaf(d0, d0, sa);
            sb = fmaf(d1, d1, sb);
        }
        ssum = wave_sum_u(sa + sb);
    } else {
        // ---- Lane-overflow fallback: full 50-iteration bisection on v ----
        float lo = -1.0f, hi = 0.0f;
        for (int it = 0; it < TOTAL_ITER; ++it) {
            const float mid = 0.5f * (lo + hi);
            float s0 = 0.f, s1_ = 0.f, s2_ = 0.f, s3_ = 0.f;
            #pragma unroll
            for (int i = 0; i < PER_LANE; i += 4) {
                float d0 = fmaxf(v[i+0] - mid, 0.f);
                float d1 = fmaxf(v[i+1] - mid, 0.f);
                float d2 = fmaxf(v[i+2] - mid, 0.f);
                float d3 = fmaxf(v[i+3] - mid, 0.f);
                s0 = fmaf(d0, d0, s0); s1_ = fmaf(d1, d1, s1_);
                s2_ = fmaf(d2, d2, s2_); s3_ = fmaf(d3, d3, s3_);
            }
            const float s = wave_sum_u((s0 + s1_) + (s2_ + s3_));
            const bool gt = s > 1.0f;
            lo = gt ? mid : lo;
            hi = gt ? hi : mid;
        }
        tau = 0.5f * (lo + hi);
        float s0 = 0.f;
        #pragma unroll
        for (int i = 0; i < PER_LANE; ++i) {
            float d = fmaxf(v[i] - tau, 0.f);
            s0 = fmaf(d, d, s0);
        }
        ssum = wave_sum_u(s0);
    }

    // ---- Epilogue: p = max(v - tau, 0)^2 * inv ----
    const float inv = 1.0f / fmaxf(ssum, 1e-12f);
    #pragma unroll
    for (int c = 0; c < PER_LANE / 4; ++c) {
        float d0 = fmaxf(v[4*c+0] - tau, 0.f);
        float d1 = fmaxf(v[4*c+1] - tau, 0.f);
        float d2 = fmaxf(v[4*c+2] - tau, 0.f);
        float d3 = fmaxf(v[4*c+3] - tau, 0.f);
        f32x4 t;
        t.x = (d0 * d0) * inv;
        t.y = (d1 * d1) * inv;
        t.z = (d2 * d2) * inv;
        t.w = (d3 * d3) * inv;
        outr[lane + 64 * c] = t;
    }
}

extern "C" void kernel_launch(void* const* d_in, const int* in_sizes, int n_in,
                              void* d_out, int out_size, void* d_ws, size_t ws_size,
                              hipStream_t stream) {
    const float* x = (const float*)d_in[0];
    float* out = (float*)d_out;
    const int rows = in_sizes[0] / N;                 // 16384
    const int blocks = (rows + WPB - 1) / WPB;        // 4096
    entmax15_kernel<<<blocks, 64 * WPB, 0, stream>>>(x, out, rows);
}

// Round 10
// 52.532 us; speedup vs baseline: 1.6925x; 1.0049x over previous
//
#include <hip/hip_runtime.h>

// entmax_bisect, alpha=1.5, rows of N=2048 fp32. One wave64 per row (16384
// waves: TLP hides latency — rounds 5/6/7 proved trading wave-count for
// per-wave pipelining loses; rounds 6/8 proved the live-register budget must
// match the working set or the allocator spills/sinks).
//
// Round-10 vs round-9 (52.8us): two fast-path latency cuts.
//  (1) ssum = 1 on the closed-form path: tau is the exact root of the
//      support quadratic, so sum(p) == 1 +- ~1e-6 (reference also divides
//      by ~1.0000001). Drops the final 26-VALU + DPP-reduce chain.
//  (2) cnt-specialized boundary handling: P(cnt=0)~27%, P(cnt=1)~35% —
//      skip the 19-CE sort + 8-STEP greedy (~250 serial cyc) when possible.
//
// DPP reductions (VALU pipe, ~8 cyc/step vs ds_swizzle ~35) + readlane(63)
// -> bisection state is wave-uniform scalar.
//
// Math (validated rounds 2-9, absmax ~1e-3 vs 2e-2 threshold):
//   v = 0.5*x - 0.5*max => max element -> exactly 0; bracket (lo,hi)=(-1,0);
//   am1=0.5 => power(d,1/am1)=d*d. All midpoints and tau lie in (-1,0], so
//   elements with v <= -1 contribute exactly 0 everywhere -> compact
//   candidates (v > -1, ~140/2048 for N(0,1)) into <=12 LDS slots per lane.
//   P1: K1=6 bisect iters on candidates (bracket 2^-6), s(lo) > 1 >= s(hi).
//       (After 6 iters hi <= -1/64 always, and v_max=0 > hi => nA >= 1.)
//   P2: aggregates (n,S1,S2) over certain support {v > hi} centered at hi;
//       boundary elements in (lo,hi] compacted (<=8).
//   P3: greedy prefix-accept over sorted boundary (s monotone), closed-form
//       tau = hi + (S1 - sqrt(S1^2 - n(S2-1)))/n (== 50-iter bisection limit
//       to 2^-44 << fp32 rounding).
//   Fallbacks (exact): >12 candidates in a lane -> full 50-iter bisection on
//   v[32]; >8 boundary -> remaining bisect iters on the compacted set.

typedef float f32x4 __attribute__((ext_vector_type(4)));

constexpr int N = 2048;
constexpr int PER_LANE = N / 64;      // 32
constexpr int WPB = 4;                // waves per 256-thread block
constexpr int CAPL = 12;              // candidate capacity per lane
constexpr int BMAX = 8;
constexpr int K1 = 6;
constexpr int TOTAL_ITER = 50;

// ---- DPP wave64 reductions (VALU pipe; no ds_* latency) ----
template <int CTRL, int RMASK>
__device__ __forceinline__ float fdpp(float old, float s) {
    return __int_as_float(__builtin_amdgcn_update_dpp(
        __float_as_int(old), __float_as_int(s), CTRL, RMASK, 0xF, false));
}

// Full-wave sum; returns the total as a wave-uniform (SGPR) value.
__device__ __forceinline__ float wave_sum_u(float s) {
    s += fdpp<0xB1, 0xF>(s, s);    // quad_perm [1,0,3,2]  (xor 1)
    s += fdpp<0x4E, 0xF>(s, s);    // quad_perm [2,3,0,1]  (xor 2)
    s += fdpp<0x141, 0xF>(s, s);   // row_half_mirror      (8-group)
    s += fdpp<0x140, 0xF>(s, s);   // row_mirror           (16-group)
    s += fdpp<0x142, 0xA>(0.0f, s);// row_bcast:15 -> rows 1,3
    s += fdpp<0x143, 0xC>(0.0f, s);// row_bcast:31 -> rows 2,3
    return __int_as_float(__builtin_amdgcn_readlane(__float_as_int(s), 63));
}

// Full-wave max; returns wave-uniform max.
__device__ __forceinline__ float wave_max_u(float m) {
    m = fmaxf(m, fdpp<0xB1, 0xF>(m, m));
    m = fmaxf(m, fdpp<0x4E, 0xF>(m, m));
    m = fmaxf(m, fdpp<0x141, 0xF>(m, m));
    m = fmaxf(m, fdpp<0x140, 0xF>(m, m));
    m = fmaxf(m, fdpp<0x142, 0xA>(m, m));  // masked lanes: fmax(m,m)=m
    m = fmaxf(m, fdpp<0x143, 0xC>(m, m));
    return __int_as_float(__builtin_amdgcn_readlane(__float_as_int(m), 63));
}

// Smaller root of n*t^2 - 2*S1*t + (S2-1) = 0, shifted by cth.
__device__ __forceinline__ float quad_root(float n, float S1, float S2,
                                           float cth) {
    float disc = fmaxf(fmaf(S1, S1, -n * (S2 - 1.0f)), 0.0f);
    return cth + (S1 - sqrtf(disc)) / n;
}

__global__ __launch_bounds__(256, 4)
void entmax15_kernel(const float* __restrict__ x,
                     float* __restrict__ out, int rows) {
    __shared__ float s_cand[WPB][CAPL][64];   // slot-major: conflict-free
    __shared__ float s_bnd[WPB][BMAX];
    __shared__ int   s_cnt[WPB];

    const int wave = threadIdx.x >> 6;
    const int lane = threadIdx.x & 63;
    const int row  = blockIdx.x * WPB + wave;
    if (row >= rows) return;          // rows % WPB == 0: never divergent

    const f32x4* xr   = reinterpret_cast<const f32x4*>(x + (size_t)row * N);
    f32x4*       outr = reinterpret_cast<f32x4*>(out + (size_t)row * N);

    float v[PER_LANE];
    #pragma unroll
    for (int c = 0; c < PER_LANE / 4; ++c) {
        f32x4 t = xr[lane + 64 * c];
        v[4*c+0] = t.x; v[4*c+1] = t.y; v[4*c+2] = t.z; v[4*c+3] = t.w;
    }

    // Row max (wave-uniform scalar result).
    float ml = v[0];
    #pragma unroll
    for (int i = 1; i < PER_LANE; ++i) ml = fmaxf(ml, v[i]);
    const float m = wave_max_u(ml);

    // v = 0.5*x - 0.5*m (argmax -> exactly 0).
    const float nhm = -0.5f * m;
    #pragma unroll
    for (int i = 0; i < PER_LANE; ++i) v[i] = fmaf(0.5f, v[i], nhm);

    // ---- Candidate compaction: v > -1 into per-lane LDS slots ----
    #pragma unroll
    for (int k = 0; k < CAPL; ++k) s_cand[wave][k][lane] = -1e30f;
    if (lane < BMAX) s_bnd[wave][lane] = -1e30f;
    if (lane == 0)   s_cnt[wave] = 0;
    // Wave-private LDS: same-wave DS ordering suffices (no barriers).

    int j = 0;
    #pragma unroll
    for (int i = 0; i < PER_LANE; ++i) {
        const bool c = v[i] > -1.0f;
        const int  slot = (j < CAPL - 1) ? j : (CAPL - 1);  // clamp; ovf caught
        if (c) s_cand[wave][slot][lane] = v[i];
        j += c ? 1 : 0;
    }

    float tau, ssum;
    if (!__any(j > CAPL)) {
        float cd[CAPL];
        #pragma unroll
        for (int k = 0; k < CAPL; ++k) cd[k] = s_cand[wave][k][lane];

        // ---- P1: 6 bisect iters; lo/hi/mid wave-uniform (scalar) ----
        float lo = -1.0f, hi = 0.0f;
        #pragma unroll
        for (int it = 0; it < K1; ++it) {
            const float mid = 0.5f * (lo + hi);
            float sa = 0.f, sb = 0.f;
            #pragma unroll
            for (int k = 0; k < CAPL; k += 2) {
                float d0 = fmaxf(cd[k]   - mid, 0.f);
                float d1 = fmaxf(cd[k+1] - mid, 0.f);
                sa = fmaf(d0, d0, sa);
                sb = fmaf(d1, d1, sb);
            }
            const float s = wave_sum_u(sa + sb);     // uniform
            const bool gt = s > 1.0f;                // scalar compare
            lo = gt ? mid : lo;
            hi = gt ? hi : mid;
        }

        // ---- P2: aggregates over certain support + boundary compaction ----
        const float cth = hi, lof = lo;
        float nA = 0.f, S1 = 0.f, S2 = 0.f;
        #pragma unroll
        for (int k = 0; k < CAPL; ++k) {
            float u  = cd[k] - cth;
            float um = fmaxf(u, 0.f);
            nA += (u > 0.f) ? 1.0f : 0.0f;
            S1 += um;
            S2  = fmaf(um, um, S2);
            if (u <= 0.f && cd[k] > lof) {          // boundary: rare
                int t = atomicAdd(&s_cnt[wave], 1);
                if (t < BMAX) s_bnd[wave][t] = cd[k];
            }
        }
        nA = wave_sum_u(nA);
        S1 = wave_sum_u(S1);
        S2 = wave_sum_u(S2);

        const int cnt = s_cnt[wave];                // wave-uniform
        bool closed = true;
        #define STEP(bk) {                                              \
            float t_  = bk - cth;                                       \
            float sc_ = fmaf(t_, fmaf(nk, t_, -2.0f * S1k), S2k);       \
            bool  ac_ = sc_ < 1.0f;                                     \
            float ta_ = ac_ ? t_ : 0.0f;                                \
            nk  += ac_ ? 1.0f : 0.0f;                                   \
            S1k += ta_;                                                 \
            S2k  = fmaf(ta_, ta_, S2k); }
        if (cnt == 0) {
            // ~27% of rows: no boundary elements at all.
            tau = quad_root(nA, S1, S2, cth);
        } else if (cnt == 1) {
            // ~35% of rows: single boundary element, no sort needed.
            float nk = nA, S1k = S1, S2k = S2;
            float b0 = s_bnd[wave][0];
            STEP(b0)
            tau = quad_root(nk, S1k, S2k, cth);
        } else if (cnt <= BMAX) {
            float b0 = s_bnd[wave][0], b1 = s_bnd[wave][1];
            float b2 = s_bnd[wave][2], b3 = s_bnd[wave][3];
            float b4 = s_bnd[wave][4], b5 = s_bnd[wave][5];
            float b6 = s_bnd[wave][6], b7 = s_bnd[wave][7];
            // Sort descending (Batcher, 19 CEs); sentinels sink.
            #define CE(a, b) { float _t = fmaxf(a, b); b = fminf(a, b); a = _t; }
            CE(b0,b1) CE(b2,b3) CE(b4,b5) CE(b6,b7)
            CE(b0,b2) CE(b1,b3) CE(b4,b6) CE(b5,b7)
            CE(b1,b2) CE(b5,b6)
            CE(b0,b4) CE(b1,b5) CE(b2,b6) CE(b3,b7)
            CE(b2,b4) CE(b3,b5)
            CE(b1,b2) CE(b3,b4) CE(b5,b6)
            #undef CE
            // Greedy prefix-accept (sentinels: s=+inf => reject).
            float nk = nA, S1k = S1, S2k = S2;
            STEP(b0) STEP(b1) STEP(b2) STEP(b3)
            STEP(b4) STEP(b5) STEP(b6) STEP(b7)
            tau = quad_root(nk, S1k, S2k, cth);
        } else {
            // Boundary overflow: finish all remaining reference iterations
            // on the compacted set (non-candidates contribute exactly 0).
            closed = false;
            for (int it = 0; it < TOTAL_ITER - K1; ++it) {
                const float mid = 0.5f * (lo + hi);
                float sa = 0.f, sb = 0.f;
                #pragma unroll
                for (int k = 0; k < CAPL; k += 2) {
                    float d0 = fmaxf(cd[k]   - mid, 0.f);
                    float d1 = fmaxf(cd[k+1] - mid, 0.f);
                    sa = fmaf(d0, d0, sa);
                    sb = fmaf(d1, d1, sb);
                }
                const float s = wave_sum_u(sa + sb);
                const bool gt = s > 1.0f;
                lo = gt ? mid : lo;
                hi = gt ? hi : mid;
            }
            tau = 0.5f * (lo + hi);
        }
        #undef STEP

        if (closed) {
            // tau is the root of the accepted-support quadratic: sum(p) = 1
            // up to ~1e-6 (and the reference also divides by ~1.0000001).
            ssum = 1.0f;
        } else {
            float sa = 0.f, sb = 0.f;
            #pragma unroll
            for (int k = 0; k < CAPL; k += 2) {
                float d0 = fmaxf(cd[k]   - tau, 0.f);
                float d1 = fmaxf(cd[k+1] - tau, 0.f);
                sa = fmaf(d0, d0, sa);
                sb = fmaf(d1, d1, sb);
            }
            ssum = wave_sum_u(sa + sb);
        }
    } else {
        // ---- Lane-overflow fallback: full 50-iteration bisection on v ----
        float lo = -1.0f, hi = 0.0f;
        for (int it = 0; it < TOTAL_ITER; ++it) {
            const float mid = 0.5f * (lo + hi);
            float s0 = 0.f, s1_ = 0.f, s2_ = 0.f, s3_ = 0.f;
            #pragma unroll
            for (int i = 0; i < PER_LANE; i += 4) {
                float d0 = fmaxf(v[i+0] - mid, 0.f);
                float d1 = fmaxf(v[i+1] - mid, 0.f);
                float d2 = fmaxf(v[i+2] - mid, 0.f);
                float d3 = fmaxf(v[i+3] - mid, 0.f);
                s0 = fmaf(d0, d0, s0); s1_ = fmaf(d1, d1, s1_);
                s2_ = fmaf(d2, d2, s2_); s3_ = fmaf(d3, d3, s3_);
            }
            const float s = wave_sum_u((s0 + s1_) + (s2_ + s3_));
            const bool gt = s > 1.0f;
            lo = gt ? mid : lo;
            hi = gt ? hi : mid;
        }
        tau = 0.5f * (lo + hi);
        float s0 = 0.f;
        #pragma unroll
        for (int i = 0; i < PER_LANE; ++i) {
            float d = fmaxf(v[i] - tau, 0.f);
            s0 = fmaf(d, d, s0);
        }
        ssum = wave_sum_u(s0);
    }

    // ---- Epilogue: p = max(v - tau, 0)^2 * inv ----
    const float inv = 1.0f / fmaxf(ssum, 1e-12f);
    #pragma unroll
    for (int c = 0; c < PER_LANE / 4; ++c) {
        float d0 = fmaxf(v[4*c+0] - tau, 0.f);
        float d1 = fmaxf(v[4*c+1] - tau, 0.f);
        float d2 = fmaxf(v[4*c+2] - tau, 0.f);
        float d3 = fmaxf(v[4*c+3] - tau, 0.f);
        f32x4 t;
        t.x = (d0 * d0) * inv;
        t.y = (d1 * d1) * inv;
        t.z = (d2 * d2) * inv;
        t.w = (d3 * d3) * inv;
        outr[lane + 64 * c] = t;
    }
}

extern "C" void kernel_launch(void* const* d_in, const int* in_sizes, int n_in,
                              void* d_out, int out_size, void* d_ws, size_t ws_size,
                              hipStream_t stream) {
    const float* x = (const float*)d_in[0];
    float* out = (float*)d_out;
    const int rows = in_sizes[0] / N;                 // 16384
    const int blocks = (rows + WPB - 1) / WPB;        // 4096
    entmax15_kernel<<<blocks, 64 * WPB, 0, stream>>>(x, out, rows);
}